// Round 11
// baseline (200.833 us; speedup 1.0000x reference)
//
#include <hip/hip_runtime.h>
#include <hip/hip_bf16.h>
#include <hip/hip_fp16.h>

#define NF 20000
#define NH 40000
#define NALL 60000
#define NE 640000
#define DD 128
#define AA 64
#define NB 256
#define NSPLIT 128   // out_gemm split-K slices (atomic-free two-stage)

typedef __attribute__((ext_vector_type(8))) _Float16 f16x8;
typedef __attribute__((ext_vector_type(4))) float f32x4;

// ---------------- helpers ----------------

__device__ __forceinline__ float fast_rcp(float x) {
#if __has_builtin(__builtin_amdgcn_rcpf)
    return __builtin_amdgcn_rcpf(x);
#else
    return 1.f / x;
#endif
}

// tanh(x) = 1 - 2/(exp(2x)+1); exact at +-inf via rcp(inf)=0
__device__ __forceinline__ float tanh_fast(float x) {
    float e = __expf(2.f * x);
    return 1.f - 2.f * fast_rcp(e + 1.f);
}

// ---------------- kernels ----------------

// Detect whether index arrays are int64 (high dwords all zero) or int32.
__global__ void probe_kernel(const unsigned int* __restrict__ fci_raw,
                             int* __restrict__ flag) {
    unsigned int v = fci_raw[threadIdx.x * 2 + 1];
    unsigned long long any = __ballot(v != 0);
    if (threadIdx.x == 0) flag[0] = (any == 0ull) ? 1 : 0;  // 1 => int64
}

// fci only — cp is consumed directly (raw) by offsets_kernel.
__global__ void convert_kernel(const void* __restrict__ fci_raw,
                               int* __restrict__ fci32,
                               const int* __restrict__ flag) {
    int e = blockIdx.x * 256 + threadIdx.x;
    if (e >= NE) return;
    fci32[e] = flag[0] ? (int)((const long long*)fci_raw)[e]
                       : ((const int*)fci_raw)[e];
}

// offs[f] = lower_bound(cp, f) for f in [0, NF] — reads the RAW sorted array
// (int64 or int32 per flag), no intermediate conversion pass needed.
__global__ void offsets_kernel(const void* __restrict__ cp_raw,
                               const int* __restrict__ flag,
                               int* __restrict__ offs) {
    int f = blockIdx.x * 256 + threadIdx.x;
    if (f > NF) return;
    const bool is64 = flag[0] != 0;
    const long long* cp64 = (const long long*)cp_raw;
    const int* cp32 = (const int*)cp_raw;
    int lo = 0, hi = NE;
    while (lo < hi) {
        int mid = (lo + hi) >> 1;
        long long v = is64 ? cp64[mid] : (long long)cp32[mid];
        if (v < (long long)f) lo = mid + 1; else hi = mid;
    }
    offs[f] = lo;
}

// WtH[s][n][k] = fp16( w_kernel[s*128 + k][n] )  — transposed so MFMA B-frags
// (8 consecutive k per lane) are 16B-contiguous. s=0 -> W1, s=1 -> W2.
__global__ __launch_bounds__(256) void prep_w_kernel(
    const float* __restrict__ w_kernel, __half* __restrict__ WtH)
{
    const int t = blockIdx.x * 256 + threadIdx.x;  // < 2*64*128 = 16384
    const int s = t >> 13;
    const int n = (t >> 7) & 63;
    const int k = t & 127;
    WtH[t] = __float2half(w_kernel[(size_t)(s * 128 + k) * 64 + n]);
}

// Projection GEMM via MFMA (fp16 in, fp32 accum), with the fp32->fp16
// embedding conversion FUSED: P2 tiles read fp32 emb rows, convert in-register
// to A-frags, write embH as a side effect, and run the MFMAs. One 16-row x
// 64-col tile per wave, K=128. Tiles 0..3749: P2h (+embH) for all 60000 rows.
// Tiles 3750..4999: P1 rows (feat) + bias, fp32 output (no embH write).
// Fragment layouts: A row=lane&15 k=(lane>>4)*8+j; B col=lane&15 same k
// (from transposed WtH); C/D col=lane&15, row=(lane>>4)*4+reg (m89-verified).
__global__ __launch_bounds__(256) void proj_mfma_kernel(
    const float* __restrict__ feat_emb, const float* __restrict__ hid_emb,
    const __half* __restrict__ WtH, const float* __restrict__ w_bias,
    float* __restrict__ P1, __half* __restrict__ P2h, __half* __restrict__ embH)
{
    const int wave = threadIdx.x >> 6;
    const int lane = threadIdx.x & 63;
    const int ln = lane & 15;
    const int kh = lane >> 4;
    const int tile = blockIdx.x * 4 + wave;          // 0..4999
    const bool isP2 = tile < (NALL / 16);
    const int r0 = isP2 ? tile * 16 : (tile - NALL / 16) * 16;
    const int row = r0 + ln;
    const __half* Wt = WtH + (isP2 ? (64 * 128) : 0);
    const float* src = (isP2 && row >= NF) ? hid_emb + (size_t)(row - NF) * DD
                                           : feat_emb + (size_t)row * DD;

    f16x8 bfrag[4][4];   // [n-tile][k-chunk]
#pragma unroll
    for (int nt = 0; nt < 4; ++nt)
#pragma unroll
        for (int kc = 0; kc < 4; ++kc)
            bfrag[nt][kc] = *reinterpret_cast<const f16x8*>(
                Wt + (size_t)(nt * 16 + ln) * 128 + kc * 32 + kh * 8);

    f16x8 afrag[4];
#pragma unroll
    for (int kc = 0; kc < 4; ++kc) {
        const float4 v0 = ((const float4*)(src + kc * 32 + kh * 8))[0];
        const float4 v1 = ((const float4*)(src + kc * 32 + kh * 8))[1];
        f16x8 a;
        a[0] = (_Float16)v0.x; a[1] = (_Float16)v0.y;
        a[2] = (_Float16)v0.z; a[3] = (_Float16)v0.w;
        a[4] = (_Float16)v1.x; a[5] = (_Float16)v1.y;
        a[6] = (_Float16)v1.z; a[7] = (_Float16)v1.w;
        afrag[kc] = a;
        if (isP2)   // emit fp16 embedding table (each wave owns its 16 rows)
            *reinterpret_cast<f16x8*>(embH + (size_t)row * DD + kc * 32 + kh * 8) = a;
    }

    f32x4 acc[4];
#pragma unroll
    for (int nt = 0; nt < 4; ++nt) {
        acc[nt] = (f32x4){0.f, 0.f, 0.f, 0.f};
#pragma unroll
        for (int kc = 0; kc < 4; ++kc)
            acc[nt] = __builtin_amdgcn_mfma_f32_16x16x32_f16(
                afrag[kc], bfrag[nt][kc], acc[nt], 0, 0, 0);
    }

    if (isP2) {
#pragma unroll
        for (int nt = 0; nt < 4; ++nt)
#pragma unroll
            for (int j = 0; j < 4; ++j)
                P2h[(size_t)(r0 + kh * 4 + j) * AA + nt * 16 + ln] =
                    __float2half(acc[nt][j]);
    } else {
#pragma unroll
        for (int nt = 0; nt < 4; ++nt) {
            const float b = w_bias[nt * 16 + ln];
#pragma unroll
            for (int j = 0; j < 4; ++j)
                P1[(size_t)(r0 + kh * 4 + j) * AA + nt * 16 + ln] =
                    acc[nt][j] + b;
        }
    }
}

// Fused score + segment-softmax + aggregation (unchanged from R8: gather-BW
// bound at ~3.4TB/s effective; fp16 tables, 4 edges/step, depth-1 prefetch).
__global__ __launch_bounds__(256) void fused_agg_kernel(
    const __half* __restrict__ embH, const float* __restrict__ P1,
    const __half* __restrict__ P2h, const float* __restrict__ u_kernel,
    const float* __restrict__ corr, const int* __restrict__ offs,
    const int* __restrict__ fci32, float* __restrict__ context)
{
    const int wave = threadIdx.x >> 6;          // 0..3
    const int lane = threadIdx.x & 63;
    const int q = lane >> 4;                    // edge slot 0..3
    const int l = lane & 15;                    // dim lane
    const int f = blockIdx.x * 4 + wave;
    if (f >= NF) return;

    const int s0 = offs[f], s1 = offs[f + 1];

    const float4 p1v = ((const float4*)(P1 + (size_t)f * AA))[l];
    const float4 uv  = ((const float4*)u_kernel)[l];

    float4 acc0 = {0.f, 0.f, 0.f, 0.f};
    float4 acc1 = {0.f, 0.f, 0.f, 0.f};
    float den = 0.f;

    for (int cb = s0; cb < s1; cb += 32) {
        const int clen = min(32, s1 - cb);
        int   idxr = 0;
        float crr  = 0.f;
        if (lane < clen) {
            idxr = fci32[cb + lane];
            crr  = corr[cb + lane];
        }
        const int nit = (clen + 3) >> 2;        // slot q handles e = cb+4t+q

        int   iA  = __shfl(idxr, q);
        float crA = (q < clen) ? __shfl(crr, q) : 0.f;
        uint2 p2A = ((const uint2*)(P2h + (size_t)iA * AA))[l];
        uint4 emA = ((const uint4*)(embH + (size_t)iA * DD))[l];

        for (int t = 0; t < nit; ++t) {
            const int jn = 4 * (t + 1) + q;
            int   iB  = __shfl(idxr, jn & 31);
            float crB = __shfl(crr, jn & 31);
            if (jn >= clen) { iB = iA; crB = 0.f; }
            uint2 p2B = ((const uint2*)(P2h + (size_t)iB * AA))[l];
            uint4 emB = ((const uint4*)(embH + (size_t)iB * DD))[l];

            const float2 pa = __half22float2(*(const __half2*)&p2A.x);
            const float2 pb = __half22float2(*(const __half2*)&p2A.y);
            float part;
            part = tanh_fast(p1v.x + pa.x) * uv.x;
            part = fmaf(tanh_fast(p1v.y + pa.y), uv.y, part);
            part = fmaf(tanh_fast(p1v.z + pb.x), uv.z, part);
            part = fmaf(tanh_fast(p1v.w + pb.y), uv.w, part);
            part += __shfl_xor(part, 1);
            part += __shfl_xor(part, 2);
            part += __shfl_xor(part, 4);
            part += __shfl_xor(part, 8);
            const float sc = __expf(part) * crA;

            const float2 e0 = __half22float2(*(const __half2*)&emA.x);
            const float2 e1 = __half22float2(*(const __half2*)&emA.y);
            const float2 e2 = __half22float2(*(const __half2*)&emA.z);
            const float2 e3 = __half22float2(*(const __half2*)&emA.w);
            acc0.x = fmaf(sc, e0.x, acc0.x);
            acc0.y = fmaf(sc, e0.y, acc0.y);
            acc0.z = fmaf(sc, e1.x, acc0.z);
            acc0.w = fmaf(sc, e1.y, acc0.w);
            acc1.x = fmaf(sc, e2.x, acc1.x);
            acc1.y = fmaf(sc, e2.y, acc1.y);
            acc1.z = fmaf(sc, e3.x, acc1.z);
            acc1.w = fmaf(sc, e3.y, acc1.w);
            den += sc;

            iA = iB; crA = crB; p2A = p2B; emA = emB;
        }
    }

    acc0.x += __shfl_xor(acc0.x, 16); acc0.x += __shfl_xor(acc0.x, 32);
    acc0.y += __shfl_xor(acc0.y, 16); acc0.y += __shfl_xor(acc0.y, 32);
    acc0.z += __shfl_xor(acc0.z, 16); acc0.z += __shfl_xor(acc0.z, 32);
    acc0.w += __shfl_xor(acc0.w, 16); acc0.w += __shfl_xor(acc0.w, 32);
    acc1.x += __shfl_xor(acc1.x, 16); acc1.x += __shfl_xor(acc1.x, 32);
    acc1.y += __shfl_xor(acc1.y, 16); acc1.y += __shfl_xor(acc1.y, 32);
    acc1.z += __shfl_xor(acc1.z, 16); acc1.z += __shfl_xor(acc1.z, 32);
    acc1.w += __shfl_xor(acc1.w, 16); acc1.w += __shfl_xor(acc1.w, 32);
    den += __shfl_xor(den, 16); den += __shfl_xor(den, 32);

    if (q == 0) {
        float4 r0 = {0.f, 0.f, 0.f, 0.f};
        float4 r1 = {0.f, 0.f, 0.f, 0.f};
        if (s1 > s0) {
            const float inv = 1.f / den;
            r0.x = acc0.x * inv; r0.y = acc0.y * inv;
            r0.z = acc0.z * inv; r0.w = acc0.w * inv;
            r1.x = acc1.x * inv; r1.y = acc1.y * inv;
            r1.z = acc1.z * inv; r1.w = acc1.w * inv;
        }
        ((float4*)(context + (size_t)f * DD))[2 * l]     = r0;
        ((float4*)(context + (size_t)f * DD))[2 * l + 1] = r1;
    }
}

// Stage 1: partial[sy][b][d] += values[b][k]*context[k][d] over this k-slice.
// 128b x 128d block tile (context re-read x2 instead of x4), 8b x 8d register
// tile per thread -> 256 FMA : 16 b128 LDS per 4k window (VALU-bound).
// grid: (2 b-tiles of 128, NSPLIT k-slices). NO atomics.
__global__ __launch_bounds__(256) void out_gemm_partial(
    const float* __restrict__ values, const float* __restrict__ context,
    float* __restrict__ partial)
{
    __shared__ float vl[128][64];   // 32KB values tile [b][k]
    __shared__ float xl[64][128];   // 32KB context tile [k][d]

    const int b0 = blockIdx.x * 128;
    const int sy = blockIdx.y;
    const int s0_4 = (sy * 5000) >> 7;        // k-range in float4 units
    const int s1_4 = ((sy + 1) * 5000) >> 7;
    const int t  = threadIdx.x;
    const int dg = t & 15;          // dims dg*8 .. dg*8+7
    const int bg = t >> 4;          // rows b0 + bg*8 .. +7

    float4 acc[8][2];
#pragma unroll
    for (int i = 0; i < 8; ++i) {
        acc[i][0] = (float4){0.f, 0.f, 0.f, 0.f};
        acc[i][1] = (float4){0.f, 0.f, 0.f, 0.f};
    }

    for (int t4 = s0_4; t4 < s1_4; t4 += 16) {
        const int kt4 = min(16, s1_4 - t4);   // float4 units in this window
        __syncthreads();
        // stage values tile: 128 rows x 16 f4 slots = 2048, 8 per thread
#pragma unroll
        for (int it = 0; it < 8; ++it) {
            int idx = t + it * 256;          // 0..2047
            int bb = idx >> 4;               // 0..127
            int kq = idx & 15;               // 0..15
            if (kq < kt4)
                *(float4*)&vl[bb][kq * 4] =
                    *(const float4*)&values[(size_t)(b0 + bb) * NF + (t4 + kq) * 4];
        }
        // stage context tile: 64 k rows x 32 f4 slots = 2048, 8 per thread
#pragma unroll
        for (int it = 0; it < 8; ++it) {
            int idx = t + it * 256;          // 0..2047
            int kk = idx >> 5;               // 0..63
            int c4 = (idx & 31) * 4;
            if (kk < kt4 * 4)
                *(float4*)&xl[kk][c4] =
                    *(const float4*)&context[(size_t)(t4 * 4 + kk) * DD + c4];
        }
        __syncthreads();

        for (int k4 = 0; k4 < kt4; ++k4) {
            float4 xv[4][2];
#pragma unroll
            for (int j = 0; j < 4; ++j) {
                xv[j][0] = *(const float4*)&xl[k4 * 4 + j][dg * 8];
                xv[j][1] = *(const float4*)&xl[k4 * 4 + j][dg * 8 + 4];
            }
#pragma unroll
            for (int i = 0; i < 8; ++i) {
                const float4 vv = *(const float4*)&vl[bg * 8 + i][k4 * 4];
#pragma unroll
                for (int h = 0; h < 2; ++h) {
                    acc[i][h].x = fmaf(vv.x, xv[0][h].x, acc[i][h].x);
                    acc[i][h].y = fmaf(vv.x, xv[0][h].y, acc[i][h].y);
                    acc[i][h].z = fmaf(vv.x, xv[0][h].z, acc[i][h].z);
                    acc[i][h].w = fmaf(vv.x, xv[0][h].w, acc[i][h].w);
                    acc[i][h].x = fmaf(vv.y, xv[1][h].x, acc[i][h].x);
                    acc[i][h].y = fmaf(vv.y, xv[1][h].y, acc[i][h].y);
                    acc[i][h].z = fmaf(vv.y, xv[1][h].z, acc[i][h].z);
                    acc[i][h].w = fmaf(vv.y, xv[1][h].w, acc[i][h].w);
                    acc[i][h].x = fmaf(vv.z, xv[2][h].x, acc[i][h].x);
                    acc[i][h].y = fmaf(vv.z, xv[2][h].y, acc[i][h].y);
                    acc[i][h].z = fmaf(vv.z, xv[2][h].z, acc[i][h].z);
                    acc[i][h].w = fmaf(vv.z, xv[2][h].w, acc[i][h].w);
                    acc[i][h].x = fmaf(vv.w, xv[3][h].x, acc[i][h].x);
                    acc[i][h].y = fmaf(vv.w, xv[3][h].y, acc[i][h].y);
                    acc[i][h].z = fmaf(vv.w, xv[3][h].z, acc[i][h].z);
                    acc[i][h].w = fmaf(vv.w, xv[3][h].w, acc[i][h].w);
                }
            }
        }
    }

    float* pbase = partial + (size_t)sy * (NB * DD);
#pragma unroll
    for (int i = 0; i < 8; ++i) {
        float* o = &pbase[(size_t)(b0 + bg * 8 + i) * DD + dg * 8];
        *(float4*)(o)     = acc[i][0];
        *(float4*)(o + 4) = acc[i][1];
    }
}

// Stage 2: out[idx] = sum_s partial[s][idx]. One thread per output, no atomics.
__global__ __launch_bounds__(128) void out_reduce_kernel(
    const float* __restrict__ partial, float* __restrict__ out)
{
    const int idx = blockIdx.x * 128 + threadIdx.x;
    float s = 0.f;
#pragma unroll 8
    for (int p = 0; p < NSPLIT; ++p)
        s += partial[(size_t)p * (NB * DD) + idx];
    out[idx] = s;
}

// ---------------- launch ----------------

extern "C" void kernel_launch(void* const* d_in, const int* in_sizes, int n_in,
                              void* d_out, int out_size, void* d_ws, size_t ws_size,
                              hipStream_t stream) {
    const float* values   = (const float*)d_in[0];
    const float* feat_emb = (const float*)d_in[1];
    const float* hid_emb  = (const float*)d_in[2];
    const float* w_kernel = (const float*)d_in[3];
    const float* w_bias   = (const float*)d_in[4];
    const float* u_kernel = (const float*)d_in[5];
    const float* corr     = (const float*)d_in[6];
    const void*  cp_raw   = d_in[7];
    const void*  fci_raw  = d_in[8];
    float* out = (float*)d_out;

    char* ws = (char*)d_ws;
    size_t off = 0;
    auto alloc = [&](size_t bytes) {
        size_t cur = off;
        off += (bytes + 511) & ~size_t(511);
        return cur;
    };
    int*    flag    = (int*)   (ws + alloc(4));
    int*    fci32   = (int*)   (ws + alloc(sizeof(int) * NE));
    int*    offs    = (int*)   (ws + alloc(sizeof(int) * (NF + 1)));
    float*  P1      = (float*) (ws + alloc(sizeof(float) * (size_t)NF * AA));
    __half* P2h     = (__half*)(ws + alloc(sizeof(__half) * (size_t)NALL * AA));
    __half* embH    = (__half*)(ws + alloc(sizeof(__half) * (size_t)NALL * DD));
    __half* WtH     = (__half*)(ws + alloc(sizeof(__half) * 2 * 64 * 128));
    float*  context = (float*) (ws + alloc(sizeof(float) * (size_t)NF * DD));
    float*  partial = (float*) (ws + alloc(sizeof(float) * (size_t)NSPLIT * NB * DD));

    // 1. dtype probe, then fci conversion + raw-cp offsets (independent)
    probe_kernel<<<1, 64, 0, stream>>>((const unsigned int*)fci_raw, flag);
    convert_kernel<<<(NE + 255) / 256, 256, 0, stream>>>(fci_raw, fci32, flag);
    offsets_kernel<<<(NF + 1 + 255) / 256, 256, 0, stream>>>(cp_raw, flag, offs);

    // 2. transposed fp16 weights
    prep_w_kernel<<<(2 * 64 * 128) / 256, 256, 0, stream>>>(w_kernel, WtH);

    // 3. projections P1 / P2h via MFMA, emitting embH inline
    proj_mfma_kernel<<<(NALL / 16 + NF / 16) / 4, 256, 0, stream>>>(
        feat_emb, hid_emb, WtH, w_bias, P1, P2h, embH);

    // 4. fused score + segment softmax + weighted aggregation -> context
    fused_agg_kernel<<<(NF + 3) / 4, 256, 0, stream>>>(embH, P1, P2h,
                                                       u_kernel, corr, offs, fci32,
                                                       context);

    // 5. out = values @ context  (atomic-free two-stage split-K)
    dim3 ggrid(NB / 128, NSPLIT);
    out_gemm_partial<<<ggrid, 256, 0, stream>>>(values, context, partial);
    out_reduce_kernel<<<(NB * DD) / 128, 128, 0, stream>>>(partial, out);
}

// Round 13
// 197.391 us; speedup vs baseline: 1.0174x; 1.0174x over previous
//
#include <hip/hip_runtime.h>
#include <hip/hip_bf16.h>
#include <hip/hip_fp16.h>

#define NF 20000
#define NH 40000
#define NALL 60000
#define NE 640000
#define DD 128
#define AA 64
#define NB 256
#define NS2 125     // out_mfma split-K slices (20000 = 125 * 160)
#define KSL 160     // k per slice (5 MFMA steps of 32)

typedef __attribute__((ext_vector_type(8))) _Float16 f16x8;
typedef __attribute__((ext_vector_type(4))) float f32x4;

// ---------------- helpers ----------------

__device__ __forceinline__ float fast_rcp(float x) {
#if __has_builtin(__builtin_amdgcn_rcpf)
    return __builtin_amdgcn_rcpf(x);
#else
    return 1.f / x;
#endif
}

// tanh(x) = 1 - 2/(exp(2x)+1); exact at +-inf via rcp(inf)=0
__device__ __forceinline__ float tanh_fast(float x) {
    float e = __expf(2.f * x);
    return 1.f - 2.f * fast_rcp(e + 1.f);
}

// ---------------- kernels ----------------

// Detect whether index arrays are int64 (high dwords all zero) or int32.
__global__ void probe_kernel(const unsigned int* __restrict__ fci_raw,
                             int* __restrict__ flag) {
    unsigned int v = fci_raw[threadIdx.x * 2 + 1];
    unsigned long long any = __ballot(v != 0);
    if (threadIdx.x == 0) flag[0] = (any == 0ull) ? 1 : 0;  // 1 => int64
}

// fci only — cp is consumed directly (raw) by offsets_kernel.
__global__ void convert_kernel(const void* __restrict__ fci_raw,
                               int* __restrict__ fci32,
                               const int* __restrict__ flag) {
    int e = blockIdx.x * 256 + threadIdx.x;
    if (e >= NE) return;
    fci32[e] = flag[0] ? (int)((const long long*)fci_raw)[e]
                       : ((const int*)fci_raw)[e];
}

// offs[f] = lower_bound(cp, f) for f in [0, NF] — reads the RAW sorted array.
__global__ void offsets_kernel(const void* __restrict__ cp_raw,
                               const int* __restrict__ flag,
                               int* __restrict__ offs) {
    int f = blockIdx.x * 256 + threadIdx.x;
    if (f > NF) return;
    const bool is64 = flag[0] != 0;
    const long long* cp64 = (const long long*)cp_raw;
    const int* cp32 = (const int*)cp_raw;
    int lo = 0, hi = NE;
    while (lo < hi) {
        int mid = (lo + hi) >> 1;
        long long v = is64 ? cp64[mid] : (long long)cp32[mid];
        if (v < (long long)f) lo = mid + 1; else hi = mid;
    }
    offs[f] = lo;
}

// WtH[s][n][k] = fp16( w_kernel[s*128 + k][n] )  — transposed for MFMA B-frags.
__global__ __launch_bounds__(256) void prep_w_kernel(
    const float* __restrict__ w_kernel, __half* __restrict__ WtH)
{
    const int t = blockIdx.x * 256 + threadIdx.x;  // < 2*64*128 = 16384
    const int s = t >> 13;
    const int n = (t >> 7) & 63;
    const int k = t & 127;
    WtH[t] = __float2half(w_kernel[(size_t)(s * 128 + k) * 64 + n]);
}

// VH = fp16(values): 256 x 20000, 8 contiguous elems per thread (exact grid).
__global__ __launch_bounds__(256) void prep_v_kernel(
    const float* __restrict__ values, __half* __restrict__ VH)
{
    const int tid = blockIdx.x * 256 + threadIdx.x;   // < 640000
    const float4 v0 = ((const float4*)(values + (size_t)tid * 8))[0];
    const float4 v1 = ((const float4*)(values + (size_t)tid * 8))[1];
    union { __half2 h2[4]; uint4 u; } cv;
    cv.h2[0] = __float22half2_rn({v0.x, v0.y});
    cv.h2[1] = __float22half2_rn({v0.z, v0.w});
    cv.h2[2] = __float22half2_rn({v1.x, v1.y});
    cv.h2[3] = __float22half2_rn({v1.z, v1.w});
    *(uint4*)(VH + (size_t)tid * 8) = cv.u;
}

// Projection GEMM via MFMA (fp16 in, fp32 accum), embH conversion fused.
// Layout m89-verified via R8/R10 hardware pass.
__global__ __launch_bounds__(256) void proj_mfma_kernel(
    const float* __restrict__ feat_emb, const float* __restrict__ hid_emb,
    const __half* __restrict__ WtH, const float* __restrict__ w_bias,
    float* __restrict__ P1, __half* __restrict__ P2h, __half* __restrict__ embH)
{
    const int wave = threadIdx.x >> 6;
    const int lane = threadIdx.x & 63;
    const int ln = lane & 15;
    const int kh = lane >> 4;
    const int tile = blockIdx.x * 4 + wave;          // 0..4999
    const bool isP2 = tile < (NALL / 16);
    const int r0 = isP2 ? tile * 16 : (tile - NALL / 16) * 16;
    const int row = r0 + ln;
    const __half* Wt = WtH + (isP2 ? (64 * 128) : 0);
    const float* src = (isP2 && row >= NF) ? hid_emb + (size_t)(row - NF) * DD
                                           : feat_emb + (size_t)row * DD;

    f16x8 bfrag[4][4];   // [n-tile][k-chunk]
#pragma unroll
    for (int nt = 0; nt < 4; ++nt)
#pragma unroll
        for (int kc = 0; kc < 4; ++kc)
            bfrag[nt][kc] = *reinterpret_cast<const f16x8*>(
                Wt + (size_t)(nt * 16 + ln) * 128 + kc * 32 + kh * 8);

    f16x8 afrag[4];
#pragma unroll
    for (int kc = 0; kc < 4; ++kc) {
        const float4 v0 = ((const float4*)(src + kc * 32 + kh * 8))[0];
        const float4 v1 = ((const float4*)(src + kc * 32 + kh * 8))[1];
        f16x8 a;
        a[0] = (_Float16)v0.x; a[1] = (_Float16)v0.y;
        a[2] = (_Float16)v0.z; a[3] = (_Float16)v0.w;
        a[4] = (_Float16)v1.x; a[5] = (_Float16)v1.y;
        a[6] = (_Float16)v1.z; a[7] = (_Float16)v1.w;
        afrag[kc] = a;
        if (isP2)
            *reinterpret_cast<f16x8*>(embH + (size_t)row * DD + kc * 32 + kh * 8) = a;
    }

    f32x4 acc[4];
#pragma unroll
    for (int nt = 0; nt < 4; ++nt) {
        acc[nt] = (f32x4){0.f, 0.f, 0.f, 0.f};
#pragma unroll
        for (int kc = 0; kc < 4; ++kc)
            acc[nt] = __builtin_amdgcn_mfma_f32_16x16x32_f16(
                afrag[kc], bfrag[nt][kc], acc[nt], 0, 0, 0);
    }

    if (isP2) {
#pragma unroll
        for (int nt = 0; nt < 4; ++nt)
#pragma unroll
            for (int j = 0; j < 4; ++j)
                P2h[(size_t)(r0 + kh * 4 + j) * AA + nt * 16 + ln] =
                    __float2half(acc[nt][j]);
    } else {
#pragma unroll
        for (int nt = 0; nt < 4; ++nt) {
            const float b = w_bias[nt * 16 + ln];
#pragma unroll
            for (int j = 0; j < 4; ++j)
                P1[(size_t)(r0 + kh * 4 + j) * AA + nt * 16 + ln] =
                    acc[nt][j] + b;
        }
    }
}

// Fused score + segment-softmax + aggregation (unchanged: gather-BW bound).
__global__ __launch_bounds__(256) void fused_agg_kernel(
    const __half* __restrict__ embH, const float* __restrict__ P1,
    const __half* __restrict__ P2h, const float* __restrict__ u_kernel,
    const float* __restrict__ corr, const int* __restrict__ offs,
    const int* __restrict__ fci32, float* __restrict__ context)
{
    const int wave = threadIdx.x >> 6;          // 0..3
    const int lane = threadIdx.x & 63;
    const int q = lane >> 4;                    // edge slot 0..3
    const int l = lane & 15;                    // dim lane
    const int f = blockIdx.x * 4 + wave;
    if (f >= NF) return;

    const int s0 = offs[f], s1 = offs[f + 1];

    const float4 p1v = ((const float4*)(P1 + (size_t)f * AA))[l];
    const float4 uv  = ((const float4*)u_kernel)[l];

    float4 acc0 = {0.f, 0.f, 0.f, 0.f};
    float4 acc1 = {0.f, 0.f, 0.f, 0.f};
    float den = 0.f;

    for (int cb = s0; cb < s1; cb += 32) {
        const int clen = min(32, s1 - cb);
        int   idxr = 0;
        float crr  = 0.f;
        if (lane < clen) {
            idxr = fci32[cb + lane];
            crr  = corr[cb + lane];
        }
        const int nit = (clen + 3) >> 2;

        int   iA  = __shfl(idxr, q);
        float crA = (q < clen) ? __shfl(crr, q) : 0.f;
        uint2 p2A = ((const uint2*)(P2h + (size_t)iA * AA))[l];
        uint4 emA = ((const uint4*)(embH + (size_t)iA * DD))[l];

        for (int t = 0; t < nit; ++t) {
            const int jn = 4 * (t + 1) + q;
            int   iB  = __shfl(idxr, jn & 31);
            float crB = __shfl(crr, jn & 31);
            if (jn >= clen) { iB = iA; crB = 0.f; }
            uint2 p2B = ((const uint2*)(P2h + (size_t)iB * AA))[l];
            uint4 emB = ((const uint4*)(embH + (size_t)iB * DD))[l];

            const float2 pa = __half22float2(*(const __half2*)&p2A.x);
            const float2 pb = __half22float2(*(const __half2*)&p2A.y);
            float part;
            part = tanh_fast(p1v.x + pa.x) * uv.x;
            part = fmaf(tanh_fast(p1v.y + pa.y), uv.y, part);
            part = fmaf(tanh_fast(p1v.z + pb.x), uv.z, part);
            part = fmaf(tanh_fast(p1v.w + pb.y), uv.w, part);
            part += __shfl_xor(part, 1);
            part += __shfl_xor(part, 2);
            part += __shfl_xor(part, 4);
            part += __shfl_xor(part, 8);
            const float sc = __expf(part) * crA;

            const float2 e0 = __half22float2(*(const __half2*)&emA.x);
            const float2 e1 = __half22float2(*(const __half2*)&emA.y);
            const float2 e2 = __half22float2(*(const __half2*)&emA.z);
            const float2 e3 = __half22float2(*(const __half2*)&emA.w);
            acc0.x = fmaf(sc, e0.x, acc0.x);
            acc0.y = fmaf(sc, e0.y, acc0.y);
            acc0.z = fmaf(sc, e1.x, acc0.z);
            acc0.w = fmaf(sc, e1.y, acc0.w);
            acc1.x = fmaf(sc, e2.x, acc1.x);
            acc1.y = fmaf(sc, e2.y, acc1.y);
            acc1.z = fmaf(sc, e3.x, acc1.z);
            acc1.w = fmaf(sc, e3.y, acc1.w);
            den += sc;

            iA = iB; crA = crB; p2A = p2B; emA = emB;
        }
    }

    acc0.x += __shfl_xor(acc0.x, 16); acc0.x += __shfl_xor(acc0.x, 32);
    acc0.y += __shfl_xor(acc0.y, 16); acc0.y += __shfl_xor(acc0.y, 32);
    acc0.z += __shfl_xor(acc0.z, 16); acc0.z += __shfl_xor(acc0.z, 32);
    acc0.w += __shfl_xor(acc0.w, 16); acc0.w += __shfl_xor(acc0.w, 32);
    acc1.x += __shfl_xor(acc1.x, 16); acc1.x += __shfl_xor(acc1.x, 32);
    acc1.y += __shfl_xor(acc1.y, 16); acc1.y += __shfl_xor(acc1.y, 32);
    acc1.z += __shfl_xor(acc1.z, 16); acc1.z += __shfl_xor(acc1.z, 32);
    acc1.w += __shfl_xor(acc1.w, 16); acc1.w += __shfl_xor(acc1.w, 32);
    den += __shfl_xor(den, 16); den += __shfl_xor(den, 32);

    if (q == 0) {
        float4 r0 = {0.f, 0.f, 0.f, 0.f};
        float4 r1 = {0.f, 0.f, 0.f, 0.f};
        if (s1 > s0) {
            const float inv = 1.f / den;
            r0.x = acc0.x * inv; r0.y = acc0.y * inv;
            r0.z = acc0.z * inv; r0.w = acc0.w * inv;
            r1.x = acc1.x * inv; r1.y = acc1.y * inv;
            r1.z = acc1.z * inv; r1.w = acc1.w * inv;
        }
        ((float4*)(context + (size_t)f * DD))[2 * l]     = r0;
        ((float4*)(context + (size_t)f * DD))[2 * l + 1] = r1;
    }
}

// XT[d][f] = fp16(context[f][d]) — 64-feature x 128-dim tile per block via LDS.
// Both global sides coalesced; LDS pad 132 keeps phase-2 conflicts ~8-way.
__global__ __launch_bounds__(256) void xt_transpose_kernel(
    const float* __restrict__ context, __half* __restrict__ XT)
{
    __shared__ float lds[64][132];
    const int f0 = blockIdx.x * 64;
    const int t = threadIdx.x;

    // phase 1: load 64 rows x 128 floats, coalesced
#pragma unroll
    for (int it = 0; it < 8; ++it) {
        int idx = t + it * 256;          // 0..2047 float4 slots
        int row = idx >> 5;              // 0..63
        int c4 = (idx & 31) * 4;
        if (f0 + row < NF)
            *(float4*)&lds[row][c4] =
                *(const float4*)&context[(size_t)(f0 + row) * DD + c4];
    }
    __syncthreads();

    // phase 2: write 128 d-rows x 64 f, 8 halves per slot, coalesced
#pragma unroll
    for (int it = 0; it < 4; ++it) {
        int idx = t + it * 256;          // 0..1023 slots
        int d = idx >> 3;                // 0..127
        int fo = (idx & 7) * 8;          // 0..56
        if (f0 + fo < NF) {              // NF % 8 == 0 -> slot fully valid
            union { __half2 h2[4]; uint4 u; } cv;
#pragma unroll
            for (int j = 0; j < 4; ++j)
                cv.h2[j] = __float22half2_rn(
                    {lds[fo + 2 * j][d], lds[fo + 2 * j + 1][d]});
            *(uint4*)&XT[(size_t)d * NF + f0 + fo] = cv.u;
        }
    }
}

// out partial via MFMA: A = VH rows (b), B = XT rows (d), K = features.
// grid (4 b-tiles of 64, NS2 slices of KSL). Same frag layout as proj_mfma.
__global__ __launch_bounds__(256) void out_mfma_kernel(
    const __half* __restrict__ VH, const __half* __restrict__ XT,
    float* __restrict__ partial)
{
    const int wave = threadIdx.x >> 6;
    const int lane = threadIdx.x & 63;
    const int ln = lane & 15;
    const int kh = lane >> 4;
    const int b0 = blockIdx.x * 64;
    const int sy = blockIdx.y;
    const __half* va = VH + (size_t)(b0 + wave * 16 + ln) * NF;

    f32x4 acc[8];
#pragma unroll
    for (int nt = 0; nt < 8; ++nt) acc[nt] = (f32x4){0.f, 0.f, 0.f, 0.f};

    for (int st = 0; st < KSL / 32; ++st) {
        const int k = sy * KSL + st * 32 + kh * 8;
        const f16x8 af = *reinterpret_cast<const f16x8*>(va + k);
#pragma unroll
        for (int nt = 0; nt < 8; ++nt) {
            const f16x8 bf = *reinterpret_cast<const f16x8*>(
                XT + (size_t)(nt * 16 + ln) * NF + k);
            acc[nt] = __builtin_amdgcn_mfma_f32_16x16x32_f16(af, bf, acc[nt], 0, 0, 0);
        }
    }

    float* pbase = partial + (size_t)sy * (NB * DD);
#pragma unroll
    for (int nt = 0; nt < 8; ++nt)
#pragma unroll
        for (int j = 0; j < 4; ++j)
            pbase[(size_t)(b0 + wave * 16 + kh * 4 + j) * DD + nt * 16 + ln] =
                acc[nt][j];
}

// out[idx] = sum_s partial[s][idx]. One thread per output, no atomics.
__global__ __launch_bounds__(128) void out_reduce_kernel(
    const float* __restrict__ partial, float* __restrict__ out)
{
    const int idx = blockIdx.x * 128 + threadIdx.x;
    float s = 0.f;
#pragma unroll 5
    for (int p = 0; p < NS2; ++p)
        s += partial[(size_t)p * (NB * DD) + idx];
    out[idx] = s;
}

// ---------------- launch ----------------

extern "C" void kernel_launch(void* const* d_in, const int* in_sizes, int n_in,
                              void* d_out, int out_size, void* d_ws, size_t ws_size,
                              hipStream_t stream) {
    const float* values   = (const float*)d_in[0];
    const float* feat_emb = (const float*)d_in[1];
    const float* hid_emb  = (const float*)d_in[2];
    const float* w_kernel = (const float*)d_in[3];
    const float* w_bias   = (const float*)d_in[4];
    const float* u_kernel = (const float*)d_in[5];
    const float* corr     = (const float*)d_in[6];
    const void*  cp_raw   = d_in[7];
    const void*  fci_raw  = d_in[8];
    float* out = (float*)d_out;

    char* ws = (char*)d_ws;
    size_t off = 0;
    auto alloc = [&](size_t bytes) {
        size_t cur = off;
        off += (bytes + 511) & ~size_t(511);
        return cur;
    };
    int*    flag    = (int*)   (ws + alloc(4));
    int*    fci32   = (int*)   (ws + alloc(sizeof(int) * NE));
    int*    offs    = (int*)   (ws + alloc(sizeof(int) * (NF + 1)));
    float*  P1      = (float*) (ws + alloc(sizeof(float) * (size_t)NF * AA));
    __half* P2h     = (__half*)(ws + alloc(sizeof(__half) * (size_t)NALL * AA));
    __half* embH    = (__half*)(ws + alloc(sizeof(__half) * (size_t)NALL * DD));
    __half* WtH     = (__half*)(ws + alloc(sizeof(__half) * 2 * 64 * 128));
    __half* VH      = (__half*)(ws + alloc(sizeof(__half) * (size_t)NB * NF));
    float*  context = (float*) (ws + alloc(sizeof(float) * (size_t)NF * DD));
    __half* XT      = (__half*)(ws + alloc(sizeof(__half) * (size_t)DD * NF));
    float*  partial = (float*) (ws + alloc(sizeof(float) * (size_t)NS2 * NB * DD));

    // 1. dtype probe, fci conversion, raw-cp offsets
    probe_kernel<<<1, 64, 0, stream>>>((const unsigned int*)fci_raw, flag);
    convert_kernel<<<(NE + 255) / 256, 256, 0, stream>>>(fci_raw, fci32, flag);
    offsets_kernel<<<(NF + 1 + 255) / 256, 256, 0, stream>>>(cp_raw, flag, offs);

    // 2. fp16 prep: transposed weights + values
    prep_w_kernel<<<(2 * 64 * 128) / 256, 256, 0, stream>>>(w_kernel, WtH);
    prep_v_kernel<<<(NB * NF / 8) / 256, 256, 0, stream>>>(values, VH);

    // 3. projections P1 / P2h via MFMA, emitting embH inline
    proj_mfma_kernel<<<(NALL / 16 + NF / 16) / 4, 256, 0, stream>>>(
        feat_emb, hid_emb, WtH, w_bias, P1, P2h, embH);

    // 4. fused score + segment softmax + weighted aggregation -> context
    fused_agg_kernel<<<(NF + 3) / 4, 256, 0, stream>>>(embH, P1, P2h,
                                                       u_kernel, corr, offs, fci32,
                                                       context);

    // 5. transpose context -> XT (fp16), then out = VH @ XT^T via MFMA
    xt_transpose_kernel<<<(NF + 63) / 64, 256, 0, stream>>>(context, XT);
    dim3 ggrid(NB / 64, NS2);
    out_mfma_kernel<<<ggrid, 256, 0, stream>>>(VH, XT, partial);
    out_reduce_kernel<<<(NB * DD) / 128, 128, 0, stream>>>(partial, out);
}